// Round 11
// baseline (220.390 us; speedup 1.0000x reference)
//
#include <hip/hip_runtime.h>
#include <hip/hip_cooperative_groups.h>
#include <math.h>

#define N_NODES 10000
#define DEG1 33          // DEG + self-loop
#define D_EMB 128
#define F_IN 128
#define BATCH 2
#define NTILES 625       // virtual gemm blocks: 2 row-groups x 16 rows each

namespace cg = cooperative_groups;

typedef short s8v  __attribute__((ext_vector_type(8)));
typedef float f4v  __attribute__((ext_vector_type(4)));

// fp32 -> bf16 round-to-nearest-even (no NaN special-case; inputs are normal)
static __device__ __forceinline__ unsigned short f2bf(float f) {
    unsigned int x = __float_as_uint(f);
    unsigned int r = (x + 0x7fffu + ((x >> 16) & 1u)) >> 16;
    return (unsigned short)r;
}
static __device__ __forceinline__ float rdlane_f(float v, int l) {
    return __uint_as_float((unsigned int)__builtin_amdgcn_readlane((int)__float_as_uint(v), l));
}

// ---------------------------------------------------------------------------
// ONE fused cooperative kernel, three phases:
//   P0: every block packs W (64KB, L2-hot) into bf16 MFMA B-fragments in LDS
//       (replaces the prep kernel + the wtf global round-trip).
//   P1: gemm h = X@W via bf16 MFMA, grid-stride over 625 virtual tiles
//       (tile = 16 rows x 128 cols, 2 col-half waves). Epilogue: s/d dots,
//       per-row absmax, int8 quantize h -> hb8[(n*2+b)*128+col],
//       pk4[n]={d0,d1,scale0,scale1}, s2[n]={s0,s1}.
//   grid.sync()
//   P2: agg, wave-per-node grid-stride: scores+denom (batch-0 denom, ref
//       semantics) -> per-edge SGPR weights via readlane; ONE dword/lane
//       gather covers both batches' int8 rows; -128 bias folds into a
//       wave-uniform constant; batches combined via shfl_xor(32).
// ---------------------------------------------------------------------------
__global__ __launch_bounds__(256, 2) void gat_fused_kernel(
    const float* __restrict__ X, const float* __restrict__ W,
    const float* __restrict__ Wattn, const int* __restrict__ edges,
    float* __restrict__ out,
    unsigned char* __restrict__ hb8, float* __restrict__ pk4, float* __restrict__ s2)
{
    __shared__ s8v   wfrag[2048];           // 32 KB: [(c*4+s)*64 + lane]
    __shared__ float lds_sd[2][2][2][16];   // [rowgroup][colhalf][s|d][row]
    __shared__ float lds_mx[2][2][16];      // [rowgroup][colhalf][row] absmax

    const int t    = threadIdx.x;
    const int wave = t >> 6;
    const int lane = t & 63;
    const int quad = lane >> 4;
    const int mrow = lane & 15;

    // ---------------- P0: pack W fragments into LDS ----------------
    #pragma unroll
    for (int m = 0; m < 8; ++m) {
        const int idx = t + 256 * m;        // = (c*4+s)*64 + l
        const int l = idx & 63;
        const int s = (idx >> 6) & 3;
        const int c = idx >> 8;
        s8v f;
        #pragma unroll
        for (int j = 0; j < 8; ++j) {
            const int k = s * 32 + (l >> 4) * 8 + j;
            f[j] = (short)f2bf(W[k * 128 + c * 16 + (l & 15)]);
        }
        wfrag[idx] = f;
    }
    __syncthreads();

    // ---------------- P1: gemm + quantize epilogue ----------------
    const int rg   = wave >> 1;             // row-group within tile (0,1)
    const int half = wave & 1;              // col half (0,1)
    for (int vb = blockIdx.x; vb < NTILES; vb += gridDim.x) {
        const int row0 = (vb * 2 + rg) * 16;

        f4v acc[4];
        #pragma unroll
        for (int cc = 0; cc < 4; ++cc) acc[cc] = (f4v){0.f, 0.f, 0.f, 0.f};

        const float* xrow = X + (size_t)(row0 + mrow) * F_IN;
        #pragma unroll
        for (int s = 0; s < 4; ++s) {
            const int k0 = s * 32 + quad * 8;
            const float4 xa  = *(const float4*)&xrow[k0];
            const float4 xbv = *(const float4*)&xrow[k0 + 4];
            s8v a;
            a[0] = (short)f2bf(xa.x);  a[1] = (short)f2bf(xa.y);
            a[2] = (short)f2bf(xa.z);  a[3] = (short)f2bf(xa.w);
            a[4] = (short)f2bf(xbv.x); a[5] = (short)f2bf(xbv.y);
            a[6] = (short)f2bf(xbv.z); a[7] = (short)f2bf(xbv.w);
            #pragma unroll
            for (int cc = 0; cc < 4; ++cc) {
                const s8v b = wfrag[((half * 4 + cc) * 4 + s) * 64 + lane];
                acc[cc] = __builtin_amdgcn_mfma_f32_16x16x32_bf16(a, b, acc[cc], 0, 0, 0);
            }
        }

        // partial s/d dots + partial row absmax over this wave's 64 cols
        float as[4], ad[4];
        #pragma unroll
        for (int cc = 0; cc < 4; ++cc) {
            as[cc] = Wattn[(half * 4 + cc) * 16 + mrow];
            ad[cc] = Wattn[D_EMB + (half * 4 + cc) * 16 + mrow];
        }
        #pragma unroll
        for (int r = 0; r < 4; ++r) {
            float sv = 0.f, dv = 0.f, mx = 0.f;
            #pragma unroll
            for (int cc = 0; cc < 4; ++cc) {
                sv = fmaf(acc[cc][r], as[cc], sv);
                dv = fmaf(acc[cc][r], ad[cc], dv);
                mx = fmaxf(mx, fabsf(acc[cc][r]));
            }
            #pragma unroll
            for (int off = 1; off < 16; off <<= 1) {
                sv += __shfl_xor(sv, off, 16);
                dv += __shfl_xor(dv, off, 16);
                mx = fmaxf(mx, __shfl_xor(mx, off, 16));
            }
            if (mrow == 0) {
                lds_sd[rg][half][0][quad * 4 + r] = sv;
                lds_sd[rg][half][1][quad * 4 + r] = dv;
                lds_mx[rg][half][quad * 4 + r] = mx;
            }
        }
        __syncthreads();

        // quantize + store h (int8 biased, interleaved (n,b))
        const int b = (row0 >= N_NODES) ? 1 : 0;
        #pragma unroll
        for (int r = 0; r < 4; ++r) {
            const int qr = quad * 4 + r;
            const float mx = fmaxf(fmaxf(lds_mx[rg][0][qr], lds_mx[rg][1][qr]), 1e-20f);
            const float inv_s = 127.f / mx;
            const int n = (row0 + qr) - b * N_NODES;
            unsigned char* dst = &hb8[((size_t)n * 2 + b) * D_EMB + half * 64 + mrow];
            #pragma unroll
            for (int cc = 0; cc < 4; ++cc) {
                const float tq = fminf(fmaxf(acc[cc][r] * inv_s, -127.f), 127.f);
                dst[cc * 16] = (unsigned char)(__float2int_rn(tq) + 128);
            }
        }

        // per-node packed params (one lane per row)
        if (t < 32) {
            const int rg2 = t >> 4, r = t & 15;
            const int row = (vb * 2 + rg2) * 16 + r;
            const int b2 = (row >= N_NODES) ? 1 : 0;
            const int n2 = row - b2 * N_NODES;
            const float s_full = lds_sd[rg2][0][0][r] + lds_sd[rg2][1][0][r];
            const float d_full = lds_sd[rg2][0][1][r] + lds_sd[rg2][1][1][r];
            const float mx = fmaxf(fmaxf(lds_mx[rg2][0][r], lds_mx[rg2][1][r]), 1e-20f);
            s2[(size_t)n2 * 2 + b2] = s_full;
            pk4[(size_t)n2 * 4 + b2] = d_full;
            pk4[(size_t)n2 * 4 + 2 + b2] = mx * (1.f / 127.f);
        }
        __syncthreads();   // lds_sd/lds_mx reused next iteration
    }

    __threadfence();                  // make P1 stores device-visible
    cg::this_grid().sync();

    // ---------------- P2: edge aggregation ----------------
    const int nwaves = gridDim.x * 4;
    for (int i = blockIdx.x * 4 + wave; i < N_NODES; i += nwaves) {
        int dstv = 0; float sc0 = 0.f, wS0 = 0.f, wS1 = 0.f;
        if (lane < DEG1) {
            dstv = edges[((size_t)i * DEG1 + lane) * 2 + 1];
            const float4 pk = *(const float4*)&pk4[(size_t)dstv * 4]; // {d0,d1,sc0,sc1}
            const float2 ss = *(const float2*)&s2[(size_t)i * 2];
            float x0 = ss.x + pk.x;
            float x1 = ss.y + pk.y;
            x0 = (x0 >= 0.f) ? x0 : 0.2f * x0;            // leaky_relu(0.2)
            x1 = (x1 >= 0.f) ? x1 : 0.2f * x1;
            sc0 = __expf(fminf(fmaxf(x0, -2.f), 2.f));
            const float sc1 = __expf(fminf(fmaxf(x1, -2.f), 2.f));
            wS0 = sc0 * pk.z;            // attn-numerator * dequant scale
            wS1 = sc1 * pk.w;
        }
        float dsum = sc0;              // denom from batch 0 only (ref semantics)
        #pragma unroll
        for (int off = 1; off < 64; off <<= 1) dsum += __shfl_xor(dsum, off, 64);
        const float inv = 1.f / dsum;
        wS0 *= inv;
        wS1 *= inv;
        float csum = wS0 + wS1;        // for the -128 bias correction
        #pragma unroll
        for (int off = 1; off < 64; off <<= 1) csum += __shfl_xor(csum, off, 64);
        const float C = 128.f * csum;

        // lanes 0..31: batch-0 dims 4*dl..4*dl+3; lanes 32..63: batch-1 same
        float4 acc = make_float4(0.f, 0.f, 0.f, 0.f);
        const unsigned int* __restrict__ h4 = (const unsigned int*)hb8;
        #pragma unroll
        for (int j = 0; j < DEG1; ++j) {
            const int   dd = __builtin_amdgcn_readlane(dstv, j);   // SGPR
            const float w0 = rdlane_f(wS0, j);                     // SGPR
            const float w1 = rdlane_f(wS1, j);                     // SGPR
            const float wgt = (lane < 32) ? w0 : w1;
            const unsigned int u = h4[(size_t)dd * 64 + lane];     // saddr + lane*4
            acc.x = fmaf(wgt, (float)(u & 0xffu), acc.x);
            acc.y = fmaf(wgt, (float)((u >> 8) & 0xffu), acc.y);
            acc.z = fmaf(wgt, (float)((u >> 16) & 0xffu), acc.z);
            acc.w = fmaf(wgt, (float)(u >> 24), acc.w);
        }
        float4 o;
        o.x = acc.x + __shfl_xor(acc.x, 32, 64) - C;
        o.y = acc.y + __shfl_xor(acc.y, 32, 64) - C;
        o.z = acc.z + __shfl_xor(acc.z, 32, 64) - C;
        o.w = acc.w + __shfl_xor(acc.w, 32, 64) - C;

        const int b  = lane >> 5;        // which batch's copy this lane writes
        const int dl = lane & 31;        // dim group
        *(float4*)&out[((size_t)b * N_NODES + i) * D_EMB + dl * 4] = o;
    }
}

extern "C" void kernel_launch(void* const* d_in, const int* in_sizes, int n_in,
                              void* d_out, int out_size, void* d_ws, size_t ws_size,
                              hipStream_t stream) {
    const float* X     = (const float*)d_in[0];   // (2, 10000, 128) fp32
    const float* W     = (const float*)d_in[1];   // (128, 128) fp32
    const float* Wattn = (const float*)d_in[2];   // (256, 1) fp32
    const int*   edges = (const int*)d_in[3];     // (330000, 2) int32
    float* out = (float*)d_out;                   // (2, 10000, 128) fp32

    unsigned char* hb8 = (unsigned char*)d_ws;                    // 2.56 MB int8 h
    float* pk4 = (float*)(hb8 + (size_t)BATCH * N_NODES * D_EMB); // {d0,d1,s0,s1}/node
    float* s2  = pk4 + (size_t)N_NODES * 4;                       // {s0,s1}/node

    // co-residency-safe grid for the cooperative launch (deterministic query)
    int occ = 0;
    if (hipOccupancyMaxActiveBlocksPerMultiprocessor(&occ, gat_fused_kernel, 256, 0)
            != hipSuccess || occ < 1) occ = 1;
    if (occ > 4) occ = 4;
    int grid = 256 * occ;

    void* args[] = {(void*)&X, (void*)&W, (void*)&Wattn, (void*)&edges,
                    (void*)&out, (void*)&hb8, (void*)&pk4, (void*)&s2};
    hipLaunchCooperativeKernel((const void*)gat_fused_kernel, dim3(grid), dim3(256),
                               args, 0, stream);
}

// Round 12
// 85.886 us; speedup vs baseline: 2.5661x; 2.5661x over previous
//
#include <hip/hip_runtime.h>
#include <math.h>

#define N_NODES 10000
#define DEG1 33          // DEG + self-loop
#define D_EMB 128
#define F_IN 128
#define BATCH 2

typedef short s8v  __attribute__((ext_vector_type(8)));
typedef float f4v  __attribute__((ext_vector_type(4)));

// fp32 -> bf16 round-to-nearest-even (no NaN special-case; inputs are normal)
static __device__ __forceinline__ unsigned short f2bf(float f) {
    unsigned int x = __float_as_uint(f);
    unsigned int r = (x + 0x7fffu + ((x >> 16) & 1u)) >> 16;
    return (unsigned short)r;
}
static __device__ __forceinline__ float rdlane_f(float v, int l) {
    return __uint_as_float((unsigned int)__builtin_amdgcn_readlane((int)__float_as_uint(v), l));
}

// ---------------------------------------------------------------------------
// Kernel 1: h = X @ W via bf16 MFMA, with W-fragment packing FUSED in
// (replaces the separate prep kernel + wtf global round-trip; W is 64KB and
// L2-hot across the 625 blocks). Tile = 16 rows x 128 cols; 2 row-groups x
// 2 col-half waves per 256-thr block. Epilogue: s/d dots, per-row absmax,
// int8 biased quantize h -> hb8[(n*2+b)*128+col] (one dword/lane covers both
// batches in the agg gather), pk4[n]={d0,d1,scale0,scale1}, s2[n]={s0,s1}.
// ---------------------------------------------------------------------------
__global__ __launch_bounds__(256) void gat_h_kernel(
    const float* __restrict__ X, const float* __restrict__ W,
    const float* __restrict__ Wattn,
    unsigned char* __restrict__ hb8, float* __restrict__ pk4, float* __restrict__ s2)
{
    __shared__ s8v   wfrag[2048];           // 32 KB: [(c*4+s)*64 + lane]
    __shared__ float lds_sd[2][2][2][16];   // [rowgroup][colhalf][s|d][row]
    __shared__ float lds_mx[2][2][16];      // [rowgroup][colhalf][row] absmax

    const int t    = threadIdx.x;
    const int wave = t >> 6;
    const int lane = t & 63;
    const int quad = lane >> 4;
    const int mrow = lane & 15;

    // ---- pack W fragments into LDS (B-frag for mfma_f32_16x16x32_bf16:
    //      B[k = s*32 + (l>>4)*8 + j][n = c*16 + (l&15)]) ----
    #pragma unroll
    for (int m = 0; m < 8; ++m) {
        const int idx = t + 256 * m;        // = (c*4+s)*64 + l
        const int l = idx & 63;
        const int s = (idx >> 6) & 3;
        const int c = idx >> 8;
        s8v f;
        #pragma unroll
        for (int j = 0; j < 8; ++j) {
            const int k = s * 32 + (l >> 4) * 8 + j;
            f[j] = (short)f2bf(W[k * 128 + c * 16 + (l & 15)]);
        }
        wfrag[idx] = f;
    }
    __syncthreads();

    const int rg   = wave >> 1;             // row-group within block (0,1)
    const int half = wave & 1;              // col half (0,1)
    const int row0 = (blockIdx.x * 2 + rg) * 16;

    f4v acc[4];
    #pragma unroll
    for (int cc = 0; cc < 4; ++cc) acc[cc] = (f4v){0.f, 0.f, 0.f, 0.f};

    const float* xrow = X + (size_t)(row0 + mrow) * F_IN;
    #pragma unroll
    for (int s = 0; s < 4; ++s) {
        const int k0 = s * 32 + quad * 8;
        const float4 xa  = *(const float4*)&xrow[k0];
        const float4 xbv = *(const float4*)&xrow[k0 + 4];
        s8v a;
        a[0] = (short)f2bf(xa.x);  a[1] = (short)f2bf(xa.y);
        a[2] = (short)f2bf(xa.z);  a[3] = (short)f2bf(xa.w);
        a[4] = (short)f2bf(xbv.x); a[5] = (short)f2bf(xbv.y);
        a[6] = (short)f2bf(xbv.z); a[7] = (short)f2bf(xbv.w);
        #pragma unroll
        for (int cc = 0; cc < 4; ++cc) {
            const s8v b = wfrag[((half * 4 + cc) * 4 + s) * 64 + lane];
            acc[cc] = __builtin_amdgcn_mfma_f32_16x16x32_bf16(a, b, acc[cc], 0, 0, 0);
        }
    }

    // ---- partial s/d dots + partial row absmax over this wave's 64 cols ----
    float as[4], ad[4];
    #pragma unroll
    for (int cc = 0; cc < 4; ++cc) {
        as[cc] = Wattn[(half * 4 + cc) * 16 + mrow];
        ad[cc] = Wattn[D_EMB + (half * 4 + cc) * 16 + mrow];
    }
    #pragma unroll
    for (int r = 0; r < 4; ++r) {
        float sv = 0.f, dv = 0.f, mx = 0.f;
        #pragma unroll
        for (int cc = 0; cc < 4; ++cc) {
            sv = fmaf(acc[cc][r], as[cc], sv);
            dv = fmaf(acc[cc][r], ad[cc], dv);
            mx = fmaxf(mx, fabsf(acc[cc][r]));
        }
        #pragma unroll
        for (int off = 1; off < 16; off <<= 1) {
            sv += __shfl_xor(sv, off, 16);
            dv += __shfl_xor(dv, off, 16);
            mx = fmaxf(mx, __shfl_xor(mx, off, 16));
        }
        if (mrow == 0) {
            lds_sd[rg][half][0][quad * 4 + r] = sv;
            lds_sd[rg][half][1][quad * 4 + r] = dv;
            lds_mx[rg][half][quad * 4 + r] = mx;
        }
    }
    __syncthreads();

    // ---- quantize + store h (int8 biased, interleaved (n,b)) ----
    const int b = (row0 >= N_NODES) ? 1 : 0;
    #pragma unroll
    for (int r = 0; r < 4; ++r) {
        const int qr = quad * 4 + r;
        const float mx = fmaxf(fmaxf(lds_mx[rg][0][qr], lds_mx[rg][1][qr]), 1e-20f);
        const float inv_s = 127.f / mx;
        const int n = (row0 + qr) - b * N_NODES;
        unsigned char* dst = &hb8[((size_t)n * 2 + b) * D_EMB + half * 64 + mrow];
        #pragma unroll
        for (int cc = 0; cc < 4; ++cc) {
            const float tq = fminf(fmaxf(acc[cc][r] * inv_s, -127.f), 127.f);
            dst[cc * 16] = (unsigned char)(__float2int_rn(tq) + 128);
        }
    }

    // ---- write per-node packed params (one lane per row) ----
    if (t < 32) {
        const int rg2 = t >> 4, r = t & 15;
        const int row = (blockIdx.x * 2 + rg2) * 16 + r;
        const int b2 = (row >= N_NODES) ? 1 : 0;
        const int n2 = row - b2 * N_NODES;
        const float s_full = lds_sd[rg2][0][0][r] + lds_sd[rg2][1][0][r];
        const float d_full = lds_sd[rg2][0][1][r] + lds_sd[rg2][1][1][r];
        const float mx = fmaxf(fmaxf(lds_mx[rg2][0][r], lds_mx[rg2][1][r]), 1e-20f);
        s2[(size_t)n2 * 2 + b2] = s_full;
        pk4[(size_t)n2 * 4 + b2] = d_full;            // d for batch b2
        pk4[(size_t)n2 * 4 + 2 + b2] = mx * (1.f / 127.f);  // scale for batch b2
    }
}

// ---------------------------------------------------------------------------
// Kernel 2 (identical to R10): edge phase, int8 gather. Wave = node, 4
// independent waves per 256-thr block, no barriers/LDS. Per edge: ONE
// dword/lane saddr load covers both batches' int8 rows (256B total).
// Dequant scale folded into per-edge weight wS_b = attn_b * scale_b[dst]
// (attn uses batch-0 denom, ref semantics); the int8 bias (-128) collapses
// to the wave-uniform constant C = 128 * sum(wS0 + wS1).
// ---------------------------------------------------------------------------
__global__ __launch_bounds__(256) void gat_agg_kernel(
    const unsigned int* __restrict__ h4,   // int8 rows as dwords
    const float* __restrict__ pk4, const float* __restrict__ s2,
    const int* __restrict__ edges, float* __restrict__ out)
{
    const int i = blockIdx.x * 4 + (threadIdx.x >> 6);   // node
    const int lane = threadIdx.x & 63;

    int dstv = 0; float sc0 = 0.f, wS0 = 0.f, wS1 = 0.f;
    if (lane < DEG1) {
        dstv = edges[((size_t)i * DEG1 + lane) * 2 + 1];
        const float4 pk = *(const float4*)&pk4[(size_t)dstv * 4]; // {d0,d1,sc0,sc1}
        const float2 ss = *(const float2*)&s2[(size_t)i * 2];
        float x0 = ss.x + pk.x;
        float x1 = ss.y + pk.y;
        x0 = (x0 >= 0.f) ? x0 : 0.2f * x0;            // leaky_relu(0.2)
        x1 = (x1 >= 0.f) ? x1 : 0.2f * x1;
        sc0 = __expf(fminf(fmaxf(x0, -2.f), 2.f));
        const float sc1 = __expf(fminf(fmaxf(x1, -2.f), 2.f));
        wS0 = sc0 * pk.z;            // attn-numerator * dequant scale
        wS1 = sc1 * pk.w;
    }
    float dsum = sc0;              // denom from batch 0 only (ref semantics)
    #pragma unroll
    for (int off = 1; off < 64; off <<= 1) dsum += __shfl_xor(dsum, off, 64);
    const float inv = 1.f / dsum;
    wS0 *= inv;
    wS1 *= inv;
    float csum = wS0 + wS1;        // for the -128 bias correction
    #pragma unroll
    for (int off = 1; off < 64; off <<= 1) csum += __shfl_xor(csum, off, 64);
    const float C = 128.f * csum;

    // lanes 0..31: batch-0 dims 4*dl..4*dl+3; lanes 32..63: batch-1 same dims
    float4 acc = make_float4(0.f, 0.f, 0.f, 0.f);
    #pragma unroll
    for (int j = 0; j < DEG1; ++j) {
        const int   dd = __builtin_amdgcn_readlane(dstv, j);   // SGPR
        const float w0 = rdlane_f(wS0, j);                     // SGPR
        const float w1 = rdlane_f(wS1, j);                     // SGPR
        const float wgt = (lane < 32) ? w0 : w1;
        const unsigned int u = h4[(size_t)dd * 64 + lane];     // saddr + lane*4
        acc.x = fmaf(wgt, (float)(u & 0xffu), acc.x);
        acc.y = fmaf(wgt, (float)((u >> 8) & 0xffu), acc.y);
        acc.z = fmaf(wgt, (float)((u >> 16) & 0xffu), acc.z);
        acc.w = fmaf(wgt, (float)(u >> 24), acc.w);
    }
    // combine batches (partner lane ^32 holds the other batch, same dims),
    // then subtract the bias correction
    float4 o;
    o.x = acc.x + __shfl_xor(acc.x, 32, 64) - C;
    o.y = acc.y + __shfl_xor(acc.y, 32, 64) - C;
    o.z = acc.z + __shfl_xor(acc.z, 32, 64) - C;
    o.w = acc.w + __shfl_xor(acc.w, 32, 64) - C;

    const int b  = lane >> 5;        // which batch's copy this lane writes
    const int dl = lane & 31;        // dim group
    *(float4*)&out[((size_t)b * N_NODES + i) * D_EMB + dl * 4] = o;
}

extern "C" void kernel_launch(void* const* d_in, const int* in_sizes, int n_in,
                              void* d_out, int out_size, void* d_ws, size_t ws_size,
                              hipStream_t stream) {
    const float* X     = (const float*)d_in[0];   // (2, 10000, 128) fp32
    const float* W     = (const float*)d_in[1];   // (128, 128) fp32
    const float* Wattn = (const float*)d_in[2];   // (256, 1) fp32
    const int*   edges = (const int*)d_in[3];     // (330000, 2) int32
    float* out = (float*)d_out;                   // (2, 10000, 128) fp32

    unsigned char* hb8 = (unsigned char*)d_ws;                    // 2.56 MB int8 h
    float* pk4 = (float*)(hb8 + (size_t)BATCH * N_NODES * D_EMB); // {d0,d1,s0,s1}/node
    float* s2  = pk4 + (size_t)N_NODES * 4;                       // {s0,s1}/node

    gat_h_kernel<<<625, 256, 0, stream>>>(X, W, Wattn, hb8, pk4, s2);
    gat_agg_kernel<<<N_NODES / 4, 256, 0, stream>>>((const unsigned int*)hb8, pk4, s2, edges, out);
}